// Round 1
// baseline (1034.728 us; speedup 1.0000x reference)
//
#include <hip/hip_runtime.h>
#include <math.h>

#define HID 64
#define G4 256
#define TSTEPS 256
#define BATCH 64
#define MTOT 16384
#define NVOCAB 8000

__device__ __forceinline__ float tanh_s(float x){
    float ax = fabsf(x);
    float e = __expf(-2.0f*ax);
    float t = (1.0f - e)/(1.0f + e);
    return x >= 0.f ? t : -t;
}

// dst[C][R] = src[R][C]
__global__ void transpose_k(const float* __restrict__ src, float* __restrict__ dst, int R, int C){
    int idx = blockIdx.x*256 + threadIdx.x;
    if (idx < R*C){
        int c = idx / R;
        int r = idx - c*R;
        dst[idx] = src[r*C + c];
    }
}

__global__ void bsum_k(const float* __restrict__ a, const float* __restrict__ b, float* __restrict__ o, int n){
    int i = blockIdx.x*256 + threadIdx.x;
    if (i < n) o[i] = a[i] + b[i];
}

// C[M][N] = A[M][KTOT] * Bt[KTOT][N] + bias[N]
// 128x128 tile, 8x8 micro-tile per thread (v-halves at n0+tx*4 and n0+64+tx*4)
template<int KTOT>
__global__ __launch_bounds__(256) void gemm_bias(
    const float* __restrict__ A, const float* __restrict__ Bt,
    const float* __restrict__ bias, float* __restrict__ C,
    int M, int N)
{
    __shared__ float As[128][65];   // [m][k], stride 65 -> conflict-free b32 reads
    __shared__ float Bs[64][128];   // [k][n]
    const int tid = threadIdx.x;
    const int tx = tid & 15;        // v group
    const int ty = tid >> 4;        // m group (0..15)
    const int m0 = blockIdx.y * 128;
    const int n0 = blockIdx.x * 128;

    float4 acc0[8], acc1[8];
    #pragma unroll
    for (int i = 0; i < 8; i++){
        acc0[i] = make_float4(0.f,0.f,0.f,0.f);
        acc1[i] = make_float4(0.f,0.f,0.f,0.f);
    }

    for (int k0 = 0; k0 < KTOT; k0 += 64){
        // load A tile 128m x 64k (transposed-in-place layout [m][k])
        {
            const int mi_b = tid >> 4;          // 0..15
            const int k4   = (tid & 15) * 4;    // 0..60
            #pragma unroll
            for (int it = 0; it < 8; it++){
                int mi = it*16 + mi_b;
                float4 v = *(const float4*)(A + (size_t)(m0+mi)*KTOT + k0 + k4);
                As[mi][k4+0] = v.x; As[mi][k4+1] = v.y;
                As[mi][k4+2] = v.z; As[mi][k4+3] = v.w;
            }
        }
        // load B tile 64k x 128n
        {
            const int ki_b = tid >> 5;          // 0..7
            const int vj   = (tid & 31) * 4;    // 0..124
            #pragma unroll
            for (int it = 0; it < 8; it++){
                int ki = it*8 + ki_b;
                float4 v = make_float4(0.f,0.f,0.f,0.f);
                if (n0 + vj < N)
                    v = *(const float4*)(Bt + (size_t)(k0+ki)*N + n0 + vj);
                *(float4*)&Bs[ki][vj] = v;
            }
        }
        __syncthreads();

        #pragma unroll 8
        for (int k = 0; k < 64; k++){
            float4 b0 = *(const float4*)&Bs[k][tx*4];
            float4 b1 = *(const float4*)&Bs[k][64 + tx*4];
            #pragma unroll
            for (int i = 0; i < 8; i++){
                float av = As[ty*8+i][k];
                acc0[i].x = fmaf(av, b0.x, acc0[i].x);
                acc0[i].y = fmaf(av, b0.y, acc0[i].y);
                acc0[i].z = fmaf(av, b0.z, acc0[i].z);
                acc0[i].w = fmaf(av, b0.w, acc0[i].w);
                acc1[i].x = fmaf(av, b1.x, acc1[i].x);
                acc1[i].y = fmaf(av, b1.y, acc1[i].y);
                acc1[i].z = fmaf(av, b1.z, acc1[i].z);
                acc1[i].w = fmaf(av, b1.w, acc1[i].w);
            }
        }
        __syncthreads();
    }

    // epilogue
    const int v0a = n0 + tx*4;
    const int v0b = n0 + 64 + tx*4;
    float4 ba = make_float4(0.f,0.f,0.f,0.f);
    float4 bb = make_float4(0.f,0.f,0.f,0.f);
    if (v0a < N) ba = *(const float4*)(bias + v0a);
    if (v0b < N) bb = *(const float4*)(bias + v0b);
    #pragma unroll
    for (int i = 0; i < 8; i++){
        int m = m0 + ty*8 + i;
        float* crow = C + (size_t)m*N;
        if (v0a < N){
            float4 r;
            r.x = acc0[i].x + ba.x; r.y = acc0[i].y + ba.y;
            r.z = acc0[i].z + ba.z; r.w = acc0[i].w + ba.w;
            *(float4*)(crow + v0a) = r;
        }
        if (v0b < N){
            float4 r;
            r.x = acc1[i].x + bb.x; r.y = acc1[i].y + bb.y;
            r.z = acc1[i].z + bb.z; r.w = acc1[i].w + bb.w;
            *(float4*)(crow + v0b) = r;
        }
    }
}

// One block per batch element. 256 threads = one gate each (i:0-63,f:64-127,g:128-191,o:192-255).
// XP[b][t][256] already contains x-projection + both biases.
__global__ __launch_bounds__(256) void lstm_recur(
    const float* __restrict__ XP, const float* __restrict__ Whh,
    float* __restrict__ Hout)
{
    const int b = blockIdx.x;
    const int tid = threadIdx.x;
    __shared__ float4 hsh[16];      // h[64]
    __shared__ float gsh[256];      // activated gates

    // per-thread weight row Whh[g][0..63]
    float4 w[16];
    const float4* wr = (const float4*)(Whh + (size_t)tid*HID);
    #pragma unroll
    for (int i = 0; i < 16; i++) w[i] = wr[i];

    float c = 0.f;
    if (tid < 64) ((float*)hsh)[tid] = 0.f;
    __syncthreads();

    const float* xprow = XP + (size_t)b*TSTEPS*G4 + tid;
    const bool is_tanh = (tid >= 128) && (tid < 192);
    float xn = xprow[0];

    for (int t = 0; t < TSTEPS; t++){
        float a = xn;
        if (t+1 < TSTEPS) xn = xprow[(size_t)(t+1)*G4];   // prefetch next step

        float s0=0.f, s1=0.f, s2=0.f, s3=0.f;
        #pragma unroll
        for (int i = 0; i < 16; i += 4){
            float4 h0 = hsh[i+0];
            float4 h1 = hsh[i+1];
            float4 h2 = hsh[i+2];
            float4 h3 = hsh[i+3];
            s0 = fmaf(w[i+0].x,h0.x,s0); s0 = fmaf(w[i+0].y,h0.y,s0);
            s0 = fmaf(w[i+0].z,h0.z,s0); s0 = fmaf(w[i+0].w,h0.w,s0);
            s1 = fmaf(w[i+1].x,h1.x,s1); s1 = fmaf(w[i+1].y,h1.y,s1);
            s1 = fmaf(w[i+1].z,h1.z,s1); s1 = fmaf(w[i+1].w,h1.w,s1);
            s2 = fmaf(w[i+2].x,h2.x,s2); s2 = fmaf(w[i+2].y,h2.y,s2);
            s2 = fmaf(w[i+2].z,h2.z,s2); s2 = fmaf(w[i+2].w,h2.w,s2);
            s3 = fmaf(w[i+3].x,h3.x,s3); s3 = fmaf(w[i+3].y,h3.y,s3);
            s3 = fmaf(w[i+3].z,h3.z,s3); s3 = fmaf(w[i+3].w,h3.w,s3);
        }
        a += (s0+s1) + (s2+s3);

        // sigmoid for i,f,o; tanh for g via tanh(x)=2*sigmoid(2x)-1 (one exp for all)
        float aa = is_tanh ? 2.f*a : a;
        float sg = 1.f/(1.f + __expf(-aa));
        float act = is_tanh ? 2.f*sg - 1.f : sg;
        gsh[tid] = act;
        __syncthreads();

        if (tid < 64){
            float ig = gsh[tid];
            float fg = gsh[64+tid];
            float gg = gsh[128+tid];
            float og = gsh[192+tid];
            c = fmaf(fg, c, ig*gg);
            float hn = og * tanh_s(c);
            ((float*)hsh)[tid] = hn;
            Hout[((size_t)b*TSTEPS + t)*HID + tid] = hn;
        }
        __syncthreads();
    }
}

extern "C" void kernel_launch(void* const* d_in, const int* in_sizes, int n_in,
                              void* d_out, int out_size, void* d_ws, size_t ws_size,
                              hipStream_t stream)
{
    const float* x    = (const float*)d_in[0];
    const float* Wih0 = (const float*)d_in[1];
    const float* Whh0 = (const float*)d_in[2];
    const float* bih0 = (const float*)d_in[3];
    const float* bhh0 = (const float*)d_in[4];
    const float* Wih1 = (const float*)d_in[5];
    const float* Whh1 = (const float*)d_in[6];
    const float* bih1 = (const float*)d_in[7];
    const float* bhh1 = (const float*)d_in[8];
    const float* Wl   = (const float*)d_in[9];
    const float* bl   = (const float*)d_in[10];
    float* out = (float*)d_out;

    float* ws  = (float*)d_ws;
    float* Wt0 = ws;                  // [256][256]  = 65536
    float* Wt1 = Wt0 + 65536;         // [64][256]   = 16384
    float* WlT = Wt1 + 16384;         // [64][8000]  = 512000
    float* bs0 = WlT + 512000;        // 256
    float* bs1 = bs0 + 256;           // 256
    float* xp0 = bs1 + 256;           // [16384][256]
    float* xp1 = xp0 + 4194304;       // [16384][256]
    float* h1  = xp1 + 4194304;       // [16384][64]
    float* h2  = h1  + 1048576;       // [16384][64]

    // prep: transposes + fused biases
    transpose_k<<<256, 256, 0, stream>>>(Wih0, Wt0, 256, 256);
    transpose_k<<<64,  256, 0, stream>>>(Wih1, Wt1, 256, 64);
    transpose_k<<<2000,256, 0, stream>>>(Wl,   WlT, 8000, 64);
    bsum_k<<<1, 256, 0, stream>>>(bih0, bhh0, bs0, 256);
    bsum_k<<<1, 256, 0, stream>>>(bih1, bhh1, bs1, 256);

    // layer 0
    gemm_bias<256><<<dim3(2,128), 256, 0, stream>>>(x, Wt0, bs0, xp0, MTOT, 256);
    lstm_recur<<<BATCH, 256, 0, stream>>>(xp0, Whh0, h1);

    // layer 1
    gemm_bias<64><<<dim3(2,128), 256, 0, stream>>>(h1, Wt1, bs1, xp1, MTOT, 256);
    lstm_recur<<<BATCH, 256, 0, stream>>>(xp1, Whh1, h2);

    // vocab projection
    gemm_bias<64><<<dim3(63,128), 256, 0, stream>>>(h2, WlT, bl, out, MTOT, NVOCAB);
}